// Round 2
// 368.188 us; speedup vs baseline: 1.0822x; 1.0822x over previous
//
#include <hip/hip_runtime.h>
#include <hip/hip_bf16.h>

#define NN 50000
#define NE 800000
#define IND 128
#define C 64       // FEAT = HID = OUT
#define NBUCK 196  // coarse buckets of 256 nodes: 196*256 = 50176 >= NN

typedef __hip_bfloat16 bf16;

__device__ __forceinline__ float to_f(float v) { return v; }
__device__ __forceinline__ float to_f(bf16 v)  { return __bfloat162float(v); }

// bf16 <-> fp32 raw helpers (H is stored as ushort bf16 internally)
__device__ __forceinline__ unsigned short f2b(float v) {
    unsigned u = __float_as_uint(v);
    return (unsigned short)((u + 0x7FFFu + ((u >> 16) & 1u)) >> 16);   // RNE
}
__device__ __forceinline__ float b2f(unsigned short u) {
    return __uint_as_float((unsigned)u << 16);
}

// --- dtype detect: float inputs fp32 (flag=1) or bf16 (flag=0)? ------------
__global__ void detect_kernel(const unsigned* __restrict__ xu, int* __restrict__ flag) {
    int lane = threadIdx.x;
    unsigned u  = xu[lane];
    unsigned ex = (u >> 7) & 0xFF;
    int vote = (ex >= 90 && ex <= 144) ? 1 : 0;
#pragma unroll
    for (int off = 32; off; off >>= 1) vote += __shfl_xor(vote, off, 64);
    if (lane == 0) *flag = (vote < 40) ? 1 : 0;
}

// --- degree histogram ------------------------------------------------------
__global__ void count_kernel(const int* __restrict__ tgt, int* __restrict__ cnt) {
    int e = blockIdx.x * blockDim.x + threadIdx.x;
    if (e < NE) atomicAdd(&cnt[tgt[e]], 1);
}

// --- multi-block scan: phase A = per-block (1024 counts) totals ------------
__global__ __launch_bounds__(256) void scanA_kernel(const int4* __restrict__ cnt4,
                                                    int* __restrict__ bsum) {
    __shared__ int ws[4];
    int tid = threadIdx.x;
    int idx = blockIdx.x * 256 + tid;
    int4 v = (idx < NN / 4) ? cnt4[idx] : make_int4(0, 0, 0, 0);
    int s = v.x + v.y + v.z + v.w;
#pragma unroll
    for (int o = 32; o; o >>= 1) s += __shfl_xor(s, o, 64);
    if ((tid & 63) == 0) ws[tid >> 6] = s;
    __syncthreads();
    if (tid == 0) bsum[blockIdx.x] = ws[0] + ws[1] + ws[2] + ws[3];
}

// --- phase C: per-block exclusive scan + base from bsum -> off -------------
__global__ __launch_bounds__(256) void scanC_kernel(const int4* __restrict__ cnt4,
                                                    const int* __restrict__ bsum,
                                                    int* __restrict__ off) {
    __shared__ int wsum[4];
    int tid = threadIdx.x, lane = tid & 63, wv = tid >> 6;
    int b = blockIdx.x;
    // block base: sum of bsum[j < b]  (each wave computes it redundantly)
    int bb = (lane < b) ? bsum[lane] : 0;   // b <= 48 < 64
#pragma unroll
    for (int o = 32; o; o >>= 1) bb += __shfl_xor(bb, o, 64);
    int idx = b * 256 + tid;
    int4 v = (idx < NN / 4) ? cnt4[idx] : make_int4(0, 0, 0, 0);
    int tot = v.x + v.y + v.z + v.w;
    int incl = tot;
#pragma unroll
    for (int d = 1; d < 64; d <<= 1) { int t = __shfl_up(incl, d, 64); if (lane >= d) incl += t; }
    if (lane == 63) wsum[wv] = incl;
    __syncthreads();
    int wbase = 0;
#pragma unroll
    for (int j = 0; j < 4; ++j) wbase += (j < wv) ? wsum[j] : 0;
    int excl = bb + wbase + incl - tot;
    if (idx < NN / 4) {
        off[4 * idx]     = excl;
        off[4 * idx + 1] = excl + v.x;
        off[4 * idx + 2] = excl + v.x + v.y;
        off[4 * idx + 3] = excl + v.x + v.y + v.z;
    }
    if (b == 0 && tid == 0) off[NN] = NE;
}

// --- binA: block-local LDS histogram + clustered append into staging -------
// record = {ea0, ea1, ea2, (tgt<<16)|src}; bucket = tgt>>8; staging region for
// bucket b starts at off[b<<8] (exact size, no overflow possible).
template <typename T>
__device__ __forceinline__ void binA_impl(int* lcnt, int* lbase,
                                          const int* __restrict__ src,
                                          const int* __restrict__ tgt,
                                          const T* __restrict__ ea,
                                          const int* __restrict__ off,
                                          int* __restrict__ ccur,
                                          float4* __restrict__ stg) {
    int tid = threadIdx.x;
    for (int i = tid; i < NBUCK; i += 256) lcnt[i] = 0;
    __syncthreads();
    int e0 = blockIdx.x * 2048;
    float ex[8], ey[8], ez[8];
    unsigned ew[8];
    int eb[8], er[8];
#pragma unroll
    for (int k = 0; k < 8; ++k) {
        int e = e0 + (k << 8) + tid;
        if (e < NE) {
            int t = tgt[e];
            int s = src[e];
            eb[k] = t >> 8;
            ew[k] = ((unsigned)t << 16) | (unsigned)s;
            ex[k] = to_f(ea[e * 3 + 0]);
            ey[k] = to_f(ea[e * 3 + 1]);
            ez[k] = to_f(ea[e * 3 + 2]);
            er[k] = atomicAdd(&lcnt[eb[k]], 1);
        } else eb[k] = -1;
    }
    __syncthreads();
    for (int i = tid; i < NBUCK; i += 256) {
        int c = lcnt[i];
        int g = c ? atomicAdd(&ccur[i], c) : 0;
        lbase[i] = off[i << 8] + g;
    }
    __syncthreads();
#pragma unroll
    for (int k = 0; k < 8; ++k) {
        if (eb[k] >= 0) {
            float4 r;
            r.x = ex[k]; r.y = ey[k]; r.z = ez[k];
            r.w = __uint_as_float(ew[k]);
            stg[lbase[eb[k]] + er[k]] = r;
        }
    }
}

__global__ __launch_bounds__(256) void binA_kernel(const int* __restrict__ src,
                                                   const int* __restrict__ tgt,
                                                   const void* ea,
                                                   const int* __restrict__ off,
                                                   const int* __restrict__ flagp,
                                                   int* __restrict__ ccur,
                                                   float4* __restrict__ stg) {
    __shared__ int lcnt[NBUCK];
    __shared__ int lbase[NBUCK];
    if (*flagp) binA_impl<float>(lcnt, lbase, src, tgt, (const float*)ea, off, ccur, stg);
    else        binA_impl<bf16>(lcnt, lbase, src, tgt, (const bf16*)ea, off, ccur, stg);
}

// --- binB: one block per bucket; contiguous read, LDS-ranked local scatter -
__global__ __launch_bounds__(256) void binB_kernel(const float4* __restrict__ stg,
                                                   const int* __restrict__ off,
                                                   float4* __restrict__ edge) {
    __shared__ int lfill[256];
    __shared__ int loff[257];
    int tid = threadIdx.x;
    int n0 = blockIdx.x << 8;
    int nn = min(256, NN - n0);
    for (int i = tid; i < nn; i += 256) lfill[i] = 0;
    for (int i = tid; i <= nn; i += 256) loff[i] = off[n0 + i];   // covers loff[nn] too
    __syncthreads();
    int cb = loff[0], ce = loff[nn];
    for (int i = cb + tid; i < ce; i += 256) {
        float4 r = stg[i];
        unsigned w = __float_as_uint(r.w);
        int l = (int)(w >> 16) & 255;           // t - n0
        int rk = atomicAdd(&lfill[l], 1);       // LDS atomic
        r.w = __uint_as_float(w & 0xFFFFu);     // final record keeps src only
        edge[loff[l] + rk] = r;
    }
}

// --- linear_pre: 64 rows/block, 4x4 register tile; H stored bf16 -----------
template <typename T>
__device__ __forceinline__ void pre_impl(float (*Xl)[132], const T* __restrict__ x,
                                         const T* __restrict__ w, const T* __restrict__ b,
                                         unsigned short* __restrict__ h) {
    int tid = threadIdx.x;
    int nb  = blockIdx.x * 64;
    if constexpr (sizeof(T) == 2) {
        const ushort4* xg = (const ushort4*)(x + (size_t)nb * IND);
        for (int j = tid; j < 64 * 32; j += 256) {
            int row = j >> 5, kk = (j & 31) * 4;
            ushort4 u = (nb + row < NN) ? xg[j] : make_ushort4(0, 0, 0, 0);
            Xl[row][kk]     = b2f(u.x);
            Xl[row][kk + 1] = b2f(u.y);
            Xl[row][kk + 2] = b2f(u.z);
            Xl[row][kk + 3] = b2f(u.w);
        }
    } else {
        const float4* xg = (const float4*)(x + (size_t)nb * IND);
        for (int j = tid; j < 64 * 32; j += 256) {
            int row = j >> 5, kk = (j & 31) * 4;
            float4 v = (nb + row < NN) ? xg[j] : make_float4(0.f, 0.f, 0.f, 0.f);
            Xl[row][kk] = v.x; Xl[row][kk + 1] = v.y; Xl[row][kk + 2] = v.z; Xl[row][kk + 3] = v.w;
        }
    }
    __syncthreads();
    int tx = tid & 15, ty = tid >> 4, c0 = tx * 4;
    float acc[4][4];
#pragma unroll
    for (int r = 0; r < 4; ++r)
#pragma unroll
        for (int j = 0; j < 4; ++j) acc[r][j] = to_f(b[c0 + j]);
    for (int k = 0; k < IND; k += 4) {
#pragma unroll
        for (int kk = 0; kk < 4; ++kk) {
            float wv[4];
#pragma unroll
            for (int j = 0; j < 4; ++j) wv[j] = to_f(w[(k + kk) * C + c0 + j]);
#pragma unroll
            for (int r = 0; r < 4; ++r) {
                float sv = Xl[ty + 16 * r][k + kk];
#pragma unroll
                for (int j = 0; j < 4; ++j) acc[r][j] += sv * wv[j];
            }
        }
    }
#pragma unroll
    for (int r = 0; r < 4; ++r) {
        int row = nb + ty + 16 * r;
        if (row < NN) {
            ushort4 uv = make_ushort4(f2b(acc[r][0]), f2b(acc[r][1]), f2b(acc[r][2]), f2b(acc[r][3]));
            *(ushort4*)(h + (size_t)row * C + c0) = uv;
        }
    }
}

__global__ __launch_bounds__(256) void pre_kernel(const void* x, const void* w, const void* b,
                                                  const int* __restrict__ flagp,
                                                  unsigned short* __restrict__ h) {
    __shared__ float Xl[64][132];
    if (*flagp) pre_impl<float>(Xl, (const float*)x, (const float*)w, (const float*)b, h);
    else        pre_impl<bf16>(Xl, (const bf16*)x, (const bf16*)w, (const bf16*)b, h);
}

// --- aggregation: one wave/node, software-pipelined, bf16 h gathers --------
__global__ __launch_bounds__(256) void agg_kernel(const unsigned short* __restrict__ hb,
                                                  const float4* __restrict__ edge,
                                                  const int* __restrict__ off,
                                                  float* __restrict__ s) {
    int f = threadIdx.x & 63;
    int n = blockIdx.x * 4 + (threadIdx.x >> 6);
    int beg = __builtin_amdgcn_readfirstlane(off[n]);
    int end = __builtin_amdgcn_readfirstlane(off[n + 1]);
    float a0 = 0.f, a1 = 0.f, a2 = 0.f;
    int e = beg;
    int m4 = beg + ((end - beg) & ~3);
    if (e < m4) {
        float4 c0 = edge[e], c1 = edge[e + 1], c2 = edge[e + 2], c3 = edge[e + 3];
        e += 4;
        for (; e < m4; e += 4) {
            float h0 = b2f(hb[(__float_as_int(c0.w) << 6) + f]);
            float h1 = b2f(hb[(__float_as_int(c1.w) << 6) + f]);
            float h2 = b2f(hb[(__float_as_int(c2.w) << 6) + f]);
            float h3 = b2f(hb[(__float_as_int(c3.w) << 6) + f]);
            float4 n0 = edge[e], n1 = edge[e + 1], n2 = edge[e + 2], n3 = edge[e + 3];
            a0 += c0.x * h0; a1 += c0.y * h0; a2 += c0.z * h0;
            a0 += c1.x * h1; a1 += c1.y * h1; a2 += c1.z * h1;
            a0 += c2.x * h2; a1 += c2.y * h2; a2 += c2.z * h2;
            a0 += c3.x * h3; a1 += c3.y * h3; a2 += c3.z * h3;
            c0 = n0; c1 = n1; c2 = n2; c3 = n3;
        }
        float h0 = b2f(hb[(__float_as_int(c0.w) << 6) + f]);
        float h1 = b2f(hb[(__float_as_int(c1.w) << 6) + f]);
        float h2 = b2f(hb[(__float_as_int(c2.w) << 6) + f]);
        float h3 = b2f(hb[(__float_as_int(c3.w) << 6) + f]);
        a0 += c0.x * h0; a1 += c0.y * h0; a2 += c0.z * h0;
        a0 += c1.x * h1; a1 += c1.y * h1; a2 += c1.z * h1;
        a0 += c2.x * h2; a1 += c2.y * h2; a2 += c2.z * h2;
        a0 += c3.x * h3; a1 += c3.y * h3; a2 += c3.z * h3;
    }
    for (; e < end; ++e) {
        float4 r = edge[e];
        float hv = b2f(hb[(__float_as_int(r.w) << 6) + f]);
        a0 += r.x * hv; a1 += r.y * hv; a2 += r.z * hv;
    }
    float iv = 1.0f / fmaxf((float)(end - beg), 1.0f);
    float* so = s + n * 192;
    so[f] = a0 * iv; so[64 + f] = a1 * iv; so[128 + f] = a2 * iv;
}

// --- dense: out = S @ W + b; MODE 0: relu -> H(bf16); MODE 1: L2-norm ------
template <typename T, int MODE>
__device__ __forceinline__ void gemm_impl(float (*Sl)[196], const float* __restrict__ s,
                                          const T* __restrict__ w, const T* __restrict__ b,
                                          unsigned short* __restrict__ hout, T* __restrict__ out) {
    int tid = threadIdx.x;
    int nb  = blockIdx.x * 64;
    const float4* sg = (const float4*)(s + (size_t)nb * 192);
    for (int j = tid; j < 64 * 48; j += 256) {
        int row = j / 48, kk = (j % 48) * 4;
        float4 v = (nb + row < NN) ? sg[j] : make_float4(0.f, 0.f, 0.f, 0.f);
        Sl[row][kk] = v.x; Sl[row][kk + 1] = v.y; Sl[row][kk + 2] = v.z; Sl[row][kk + 3] = v.w;
    }
    __syncthreads();
    int tx = tid & 15, ty = tid >> 4, c0 = tx * 4;
    float acc[4][4];
#pragma unroll
    for (int r = 0; r < 4; ++r)
#pragma unroll
        for (int j = 0; j < 4; ++j) acc[r][j] = to_f(b[c0 + j]);
    for (int k = 0; k < 192; k += 4) {
#pragma unroll
        for (int kk = 0; kk < 4; ++kk) {
            float wv[4];
#pragma unroll
            for (int j = 0; j < 4; ++j) wv[j] = to_f(w[(k + kk) * C + c0 + j]);
#pragma unroll
            for (int r = 0; r < 4; ++r) {
                float sv = Sl[ty + 16 * r][k + kk];
#pragma unroll
                for (int j = 0; j < 4; ++j) acc[r][j] += sv * wv[j];
            }
        }
    }
#pragma unroll
    for (int r = 0; r < 4; ++r) {
        int row = nb + ty + 16 * r;
        if constexpr (MODE == 0) {
            if (row < NN) {
                ushort4 uv = make_ushort4(f2b(fmaxf(acc[r][0], 0.f)), f2b(fmaxf(acc[r][1], 0.f)),
                                          f2b(fmaxf(acc[r][2], 0.f)), f2b(fmaxf(acc[r][3], 0.f)));
                *(ushort4*)(hout + (size_t)row * C + c0) = uv;
            }
        } else {
            float sq = acc[r][0] * acc[r][0] + acc[r][1] * acc[r][1]
                     + acc[r][2] * acc[r][2] + acc[r][3] * acc[r][3];
#pragma unroll
            for (int o = 1; o < 16; o <<= 1) sq += __shfl_xor(sq, o, 64);
            float innorm = 1.0f / fmaxf(sqrtf(sq), 1e-12f);
            if (row < NN) {
#pragma unroll
                for (int j = 0; j < 4; ++j) {
                    float rv = acc[r][j] * innorm;
                    if constexpr (sizeof(T) == 2) out[(size_t)row * C + c0 + j] = __float2bfloat16(rv);
                    else                          out[(size_t)row * C + c0 + j] = rv;
                }
            }
        }
    }
}

__global__ __launch_bounds__(256) void gemm_relu(const float* __restrict__ s, const void* w,
                                                 const void* b, const int* __restrict__ flagp,
                                                 unsigned short* __restrict__ hout) {
    __shared__ float Sl[64][196];
    if (*flagp) gemm_impl<float, 0>(Sl, s, (const float*)w, (const float*)b, hout, (float*)nullptr);
    else        gemm_impl<bf16, 0>(Sl, s, (const bf16*)w, (const bf16*)b, hout, (bf16*)nullptr);
}

__global__ __launch_bounds__(256) void gemm_norm(const float* __restrict__ s, const void* w,
                                                 const void* b, const int* __restrict__ flagp,
                                                 void* out) {
    __shared__ float Sl[64][196];
    if (*flagp) gemm_impl<float, 1>(Sl, s, (const float*)w, (const float*)b, nullptr, (float*)out);
    else        gemm_impl<bf16, 1>(Sl, s, (const bf16*)w, (const bf16*)b, nullptr, (bf16*)out);
}

extern "C" void kernel_launch(void* const* d_in, const int* in_sizes, int n_in,
                              void* d_out, int out_size, void* d_ws, size_t ws_size,
                              hipStream_t stream) {
    const void* x     = d_in[0];
    const int*  ei    = (const int*)d_in[1];
    const void* ea    = d_in[2];
    const void* pre_w = d_in[3];
    const void* pre_b = d_in[4];
    const void* W[3]  = {d_in[5], d_in[7], d_in[9]};
    const void* B[3]  = {d_in[6], d_in[8], d_in[10]};
    const int* src = ei;
    const int* tgt = ei + NE;

    // ws layout: EDGE f4[NE] | S f32[NN*192] (staging STG overlays S)
    //            | H bf16[NN*64] | CNT[NN] | CCUR[256] | OFF[NN+8] | BSUM[64] | FLAG
    float4*         EDGE = (float4*)d_ws;                            // 12.8 MB
    float*          S    = (float*)(EDGE + NE);                      // 38.4 MB
    float4*         STG  = (float4*)S;                               // overlay (12.8 MB)
    unsigned short* H    = (unsigned short*)(S + (size_t)NN * 192);  // 6.4 MB
    int*            CNT  = (int*)(H + (size_t)NN * C);               // 16B-aligned
    int*            CCUR = CNT + NN;
    int*            OFF  = CCUR + 256;
    int*            BSUM = OFF + NN + 8;
    int*            FLAG = BSUM + 64;

    detect_kernel<<<1, 64, 0, stream>>>((const unsigned*)x, FLAG);
    hipMemsetAsync(CNT, 0, (NN + 256) * sizeof(int), stream);   // CNT + CCUR
    count_kernel<<<(NE + 255) / 256, 256, 0, stream>>>(tgt, CNT);
    scanA_kernel<<<(NN / 4 + 255) / 256, 256, 0, stream>>>((const int4*)CNT, BSUM);
    scanC_kernel<<<(NN / 4 + 255) / 256, 256, 0, stream>>>((const int4*)CNT, BSUM, OFF);
    binA_kernel<<<(NE + 2047) / 2048, 256, 0, stream>>>(src, tgt, ea, OFF, FLAG, CCUR, STG);
    binB_kernel<<<NBUCK, 256, 0, stream>>>(STG, OFF, EDGE);
    pre_kernel<<<(NN + 63) / 64, 256, 0, stream>>>(x, pre_w, pre_b, FLAG, H);

    for (int l = 0; l < 3; ++l) {
        agg_kernel<<<NN / 4, 256, 0, stream>>>(H, EDGE, OFF, S);
        if (l < 2)
            gemm_relu<<<(NN + 63) / 64, 256, 0, stream>>>(S, W[l], B[l], FLAG, H);
        else
            gemm_norm<<<(NN + 63) / 64, 256, 0, stream>>>(S, W[l], B[l], FLAG, d_out);
    }
}